// Round 6
// baseline (1994.393 us; speedup 1.0000x reference)
//
#include <hip/hip_runtime.h>
#include <hip/hip_bf16.h>
#include <math.h>

#define N_CB   8
#define M_EMB  1024
#define D_EMB  128
#define H_LAT  64
#define B_SZ   256
#define L_PER  (B_SZ * H_LAT)
#define TOTAL_X (B_SZ * N_CB * D_EMB * H_LAT)
#define NROW   (N_CB * L_PER)              /* 131072 rows */

/* d_out layout (floats): [z_q | loss | entropy | perplexity | indices] */
#define LOSS_OFF (TOTAL_X)
#define ENT_OFF  (TOTAL_X + 1)
#define PPL_OFF  (TOTAL_X + 2)
#define IDX_OFF  (TOTAL_X + 3)

/* ws layout (4-byte units) — <= 721KB proven-safe in rounds 3/5 */
#define WS_ESQ_OFF   0
#define WS_IDX_OFF   8192
#define WS_CNT_OFF   139264
#define WS_LOSS_OFF  147456
#define WS_PCNT_OFF  147457

/* scratch carved out of d_out's z_q region (fully overwritten by scatter later):
 * pairs u32  at float-offset [0, 393216)
 * rowmin u64 at float-offset [393216, 655360)
 * ebf bf16-swizzled E images (2MB) at float-offset [655360, 1179648)  */
#define PAIR_CAP     393216
#define OUT_RMIN_F   393216
#define OUT_EBF_F    655360

#define TAU2 2e-3f

typedef __attribute__((ext_vector_type(8))) short short8;
typedef __attribute__((ext_vector_type(4))) float floatx4;

__device__ __forceinline__ unsigned int bf16rn(float f) {
    unsigned int u = __float_as_uint(f);
    return (u + 0x7FFFu + ((u >> 16) & 1u)) >> 16;   /* RNE, NaN-free inputs */
}
/* order-preserving float->u32 (handles negatives) */
__device__ __forceinline__ unsigned int fkey(float f) {
    unsigned int u = __float_as_uint(f);
    return (u & 0x80000000u) ? ~u : (u | 0x80000000u);
}

__global__ void init_ws(int* __restrict__ counts, float* __restrict__ lossacc,
                        int* __restrict__ paircnt,
                        unsigned long long* __restrict__ rowmin) {
    int t = blockIdx.x * 256 + threadIdx.x;
    if (t < NROW) rowmin[t] = ~0ull;
    if (t < N_CB * M_EMB) counts[t] = 0;
    if (t == 0) { *lossacc = 0.f; *paircnt = 0; }
}

/* one wave per embedding row: e_sq[n,m] = sum_d e^2 */
__global__ void esq_kernel(const float* __restrict__ e, float* __restrict__ esq) {
    int wave = (blockIdx.x * blockDim.x + threadIdx.x) >> 6;
    int lane = threadIdx.x & 63;
    if (wave >= N_CB * M_EMB) return;
    float2 v = reinterpret_cast<const float2*>(e + (size_t)wave * D_EMB)[lane];
    float s = v.x * v.x + v.y * v.y;
    #pragma unroll
    for (int off = 32; off; off >>= 1) s += __shfl_down(s, off);
    if (lane == 0) esq[wave] = s;
}

/* E -> bf16 pre-swizzled images (per n,mc: 128 rows x 128 k = 32KB).
 * Byte layout == vq kernel's Bs LDS layout: row*256 + ((2k) ^ ((row&15)<<4)). */
__global__ void econv_kernel(const float* __restrict__ e, char* __restrict__ ebf)
{
    int blk = blockIdx.x;              /* n*8 + mc */
    int t = threadIdx.x;
    int mrow = t & 127, kh = t >> 7;
    const float* er = e + ((size_t)(blk >> 3) * M_EMB + (blk & 7) * 128 + mrow) * D_EMB;
    char* img = ebf + (size_t)blk * 32768;
    int swz = (mrow & 15) << 4;
    #pragma unroll 4
    for (int i = 0; i < 64; i += 4) {
        int k = kh * 64 + i;
        float4 v = *reinterpret_cast<const float4*>(er + k);
        unsigned int p0 = bf16rn(v.x) | (bf16rn(v.y) << 16);
        unsigned int p1 = bf16rn(v.z) | (bf16rn(v.w) << 16);
        *reinterpret_cast<uint2*>(img + mrow * 256 + ((2 * k) ^ swz)) = make_uint2(p0, p1);
    }
}

/* MFMA distance-GEMM + argmin + candidate emission.
 * grid = 8 n x 128 ltiles = 1024 blocks, 256 thr. Block: 128 rows x 1024 m, K=128.
 * Sweep 1: running min1 (m-index embedded in low 10 mantissa bits of dist key).
 * Sweep 2: re-run MFMA, emit (row,m) pairs with dist < min1 + TAU2 for np-exact
 * rerank (every row emits >= its winner). */
__launch_bounds__(256, 2)
__global__ void vq_mfma_kernel(const float* __restrict__ x,
                               const char* __restrict__ ebf,
                               const float* __restrict__ esq,
                               int*  __restrict__ idx_ws,
                               int*  __restrict__ counts,
                               int*  __restrict__ paircnt,
                               unsigned int* __restrict__ pairs,
                               float* __restrict__ out)
{
    __shared__ __align__(16) char smem[65536];   /* As 32KB | Bs 32KB */
    __shared__ float redbuf[256];                /* [row][wc] */
    __shared__ float thrbuf[128];
    const int bid = blockIdx.x;
    const int n = bid >> 7, ltile = bid & 127;
    const int b0 = ltile * 2;
    const int t = threadIdx.x;
    const int l = t & 63, w = t >> 6;
    const int wr = w >> 1, wc = w & 1;

    /* ---- stage A: x tile 128 rows x 128 k -> bf16 swizzled ---- */
    {
        int r = t & 127, kh = t >> 7;
        int bb = r >> 6, h = r & 63;
        const float* gx = x + ((size_t)(b0 + bb) * N_CB + n) * (D_EMB * H_LAT) + h;
        int swz = (r & 15) << 4;
        char* arow = smem + r * 256;
        #pragma unroll 4
        for (int i = 0; i < 64; i += 4) {
            int k = kh * 64 + i;
            float f0 = gx[(size_t)(k + 0) * H_LAT];
            float f1 = gx[(size_t)(k + 1) * H_LAT];
            float f2 = gx[(size_t)(k + 2) * H_LAT];
            float f3 = gx[(size_t)(k + 3) * H_LAT];
            unsigned int p0 = bf16rn(f0) | (bf16rn(f1) << 16);
            unsigned int p1 = bf16rn(f2) | (bf16rn(f3) << 16);
            *reinterpret_cast<uint2*>(arow + ((2 * k) ^ swz)) = make_uint2(p0, p1);
        }
    }

    float m1[16];
    #pragma unroll
    for (int i = 0; i < 16; i++) m1[i] = INFINITY;

    const char* bimg = ebf + (size_t)(n * 8) * 32768;
    const float* esq_n = esq + n * M_EMB;

    const int lx = l & 15;
    const int rbase = wr * 64 + lx;
    const int cbase = wc * 64 + lx;
    const int kb_lane = (l >> 4) * 16;
    const int swzl = lx << 4;

    /* ---- sweep 1: argmin ---- */
    for (int mc = 0; mc < 8; ++mc) {
        __syncthreads();
        {   /* stage Bs: linear 32KB copy of pre-swizzled image */
            const int4* src = reinterpret_cast<const int4*>(bimg + mc * 32768);
            int4* dst = reinterpret_cast<int4*>(smem + 32768);
            #pragma unroll
            for (int i = 0; i < 8; i++)
                dst[i * 256 + t] = src[i * 256 + t];
        }
        __syncthreads();

        floatx4 acc[4][4];
        #pragma unroll
        for (int i = 0; i < 4; i++)
            #pragma unroll
            for (int j = 0; j < 4; j++)
                acc[i][j] = (floatx4){0.f, 0.f, 0.f, 0.f};

        #pragma unroll
        for (int kc = 0; kc < 4; ++kc) {
            const int kx = (kc * 64 + kb_lane) ^ swzl;
            short8 a[4], b[4];
            #pragma unroll
            for (int i = 0; i < 4; i++)
                a[i] = *reinterpret_cast<const short8*>(smem + (rbase + i * 16) * 256 + kx);
            #pragma unroll
            for (int j = 0; j < 4; j++)
                b[j] = *reinterpret_cast<const short8*>(smem + 32768 + (cbase + j * 16) * 256 + kx);
            #pragma unroll
            for (int i = 0; i < 4; i++)
                #pragma unroll
                for (int j = 0; j < 4; j++)
                    acc[i][j] = __builtin_amdgcn_mfma_f32_16x16x32_bf16(a[i], b[j], acc[i][j], 0, 0, 0);
        }

        const int mb = mc * 128 + cbase;
        #pragma unroll
        for (int j = 0; j < 4; j++) {
            float eq = esq_n[mb + j * 16];
            unsigned int midx = (unsigned int)(mb + j * 16);
            #pragma unroll
            for (int i = 0; i < 4; i++)
                #pragma unroll
                for (int r = 0; r < 4; r++) {
                    float dist = fmaf(-2.f, acc[i][j][r], eq);
                    float key = __uint_as_float((__float_as_uint(dist) & 0xFFFFFC00u) | midx);
                    int s = i * 4 + r;
                    m1[s] = fminf(m1[s], key);
                }
        }
    }

    /* reduce min across the 16 lanes of each l>>4 group */
    #pragma unroll
    for (int s = 0; s < 16; s++) {
        float v1 = m1[s];
        #pragma unroll
        for (int off = 1; off < 16; off <<= 1) v1 = fminf(v1, __shfl_xor(v1, off));
        m1[s] = v1;
    }
    if (lx == 0) {
        #pragma unroll
        for (int i = 0; i < 4; i++)
            #pragma unroll
            for (int r = 0; r < 4; r++) {
                int row = wr * 64 + i * 16 + (l >> 4) * 4 + r;
                redbuf[row * 2 + wc] = m1[i * 4 + r];
            }
    }
    __syncthreads();
    if (wc == 0) {
        int row = wr * 64 + l;
        float v1 = fminf(redbuf[row * 2 + 0], redbuf[row * 2 + 1]);
        int i1 = (int)(__float_as_uint(v1) & 1023u);
        int b = b0 + (row >> 6), h = row & 63;
        int lidx = b * H_LAT + h;
        idx_ws[n * L_PER + lidx] = i1;
        atomicAdd(&counts[n * M_EMB + i1], 1);
        out[IDX_OFF + (b * N_CB + n) * H_LAT + h] = (float)i1;
        thrbuf[row] = v1 + TAU2;
    }
    __syncthreads();

    /* per-thread thresholds & global row ids for my 16 fragment rows */
    float thr_r[16];
    int   rid[16];
    #pragma unroll
    for (int s = 0; s < 16; s++) {
        int row = wr * 64 + (s >> 2) * 16 + (l >> 4) * 4 + (s & 3);
        thr_r[s] = thrbuf[row];
        rid[s] = n * L_PER + (b0 + (row >> 6)) * H_LAT + (row & 63);
    }

    /* ---- sweep 2: emit candidate pairs ---- */
    for (int mc = 0; mc < 8; ++mc) {
        __syncthreads();
        {
            const int4* src = reinterpret_cast<const int4*>(bimg + mc * 32768);
            int4* dst = reinterpret_cast<int4*>(smem + 32768);
            #pragma unroll
            for (int i = 0; i < 8; i++)
                dst[i * 256 + t] = src[i * 256 + t];
        }
        __syncthreads();

        floatx4 acc[4][4];
        #pragma unroll
        for (int i = 0; i < 4; i++)
            #pragma unroll
            for (int j = 0; j < 4; j++)
                acc[i][j] = (floatx4){0.f, 0.f, 0.f, 0.f};

        #pragma unroll
        for (int kc = 0; kc < 4; ++kc) {
            const int kx = (kc * 64 + kb_lane) ^ swzl;
            short8 a[4], b[4];
            #pragma unroll
            for (int i = 0; i < 4; i++)
                a[i] = *reinterpret_cast<const short8*>(smem + (rbase + i * 16) * 256 + kx);
            #pragma unroll
            for (int j = 0; j < 4; j++)
                b[j] = *reinterpret_cast<const short8*>(smem + 32768 + (cbase + j * 16) * 256 + kx);
            #pragma unroll
            for (int i = 0; i < 4; i++)
                #pragma unroll
                for (int j = 0; j < 4; j++)
                    acc[i][j] = __builtin_amdgcn_mfma_f32_16x16x32_bf16(a[i], b[j], acc[i][j], 0, 0, 0);
        }

        const int mb = mc * 128 + cbase;
        #pragma unroll
        for (int j = 0; j < 4; j++) {
            float eq = esq_n[mb + j * 16];
            unsigned int m = (unsigned int)(mb + j * 16);
            #pragma unroll
            for (int i = 0; i < 4; i++)
                #pragma unroll
                for (int r = 0; r < 4; r++) {
                    float dist = fmaf(-2.f, acc[i][j][r], eq);
                    int s = i * 4 + r;
                    if (dist < thr_r[s]) {
                        int pos = atomicAdd(paircnt, 1);
                        if (pos < PAIR_CAP)
                            pairs[pos] = ((unsigned int)rid[s] << 10) | m;
                    }
                }
        }
    }
}

/* np-fp32-semantics distance for each candidate pair; atomicMin into per-row
 * (dist,m)-packed u64. One thread per pair. */
__global__ void pair_np_kernel(const float* __restrict__ x,
                               const float* __restrict__ emb,
                               const float* __restrict__ esq,
                               const int* __restrict__ paircnt,
                               const unsigned int* __restrict__ pairs,
                               unsigned long long* __restrict__ rowmin)
{
    int np = *paircnt;
    if (np > PAIR_CAP) np = PAIR_CAP;
    for (int p = blockIdx.x * blockDim.x + threadIdx.x; p < np;
         p += gridDim.x * blockDim.x) {
        unsigned int pr = pairs[p];
        int rid = pr >> 10, m = pr & 1023;
        int n = rid >> 14, lrow = rid & (L_PER - 1);
        int b = lrow >> 6, h = lrow & 63;
        const float* xb = x + ((size_t)b * N_CB + n) * (D_EMB * H_LAT) + h;
        float xr[128];
        #pragma unroll
        for (int d = 0; d < 128; d++) xr[d] = xb[(size_t)d * H_LAT];
        double s = 0.0;
        #pragma unroll
        for (int d = 0; d < 128; d++) s += (double)xr[d] * xr[d];
        float xsq = (float)s;

        const float* er = emb + ((size_t)n * M_EMB + m) * D_EMB;
        float a0 = 0.f, a1 = 0.f, a2 = 0.f, a3 = 0.f;
        #pragma unroll 8
        for (int i = 0; i < 128; i += 4) {
            a0 = __fadd_rn(a0, __fmul_rn(xr[i + 0], er[i + 0]));
            a1 = __fadd_rn(a1, __fmul_rn(xr[i + 1], er[i + 1]));
            a2 = __fadd_rn(a2, __fmul_rn(xr[i + 2], er[i + 2]));
            a3 = __fadd_rn(a3, __fmul_rn(xr[i + 3], er[i + 3]));
        }
        float cr   = __fadd_rn(__fadd_rn(a0, a1), __fadd_rn(a2, a3));
        float t1   = __fadd_rn(esq[n * M_EMB + m], xsq);
        float dist = __fadd_rn(t1, __fmul_rn(-2.f, cr));
        unsigned long long key =
            ((unsigned long long)fkey(dist) << 32) | (unsigned long long)m;
        atomicMin(&rowmin[rid], key);
    }
}

/* apply np-exact winner per row (update idx/counts/index-output on change) */
__global__ void apply_fix_kernel(const unsigned long long* __restrict__ rowmin,
                                 int* __restrict__ idx_ws,
                                 int* __restrict__ counts,
                                 float* __restrict__ out)
{
    int rid = blockIdx.x * 256 + threadIdx.x;
    if (rid >= NROW) return;
    unsigned long long key = rowmin[rid];
    if (key == ~0ull) return;
    int m = (int)(key & 1023u);
    int old = idx_ws[rid];
    if (old != m) {
        int n = rid >> 14, lrow = rid & (L_PER - 1);
        idx_ws[rid] = m;
        atomicSub(&counts[n * M_EMB + old], 1);
        atomicAdd(&counts[n * M_EMB + m], 1);
        int b = lrow >> 6, h = lrow & 63;
        out[IDX_OFF + (b * N_CB + n) * H_LAT + h] = (float)m;
    }
}

/* z_q scatter + commitment loss. Block per (b,n): coalesced emb row gather
 * -> LDS (pitch 129) -> coalesced float4 writes. */
__global__ void scatter_loss_kernel(const float* __restrict__ x,
                                    const float* __restrict__ emb,
                                    const int* __restrict__ idx_ws,
                                    float* __restrict__ out,
                                    float* __restrict__ lossacc)
{
    __shared__ float q[64][129];
    __shared__ int   idxs[64];
    __shared__ float wsum[4];
    int bid = blockIdx.x;
    int n = bid & 7, b = bid >> 3;
    int t = threadIdx.x, lane = t & 63, w = t >> 6;

    if (t < 64) idxs[t] = idx_ws[n * L_PER + b * H_LAT + t];
    __syncthreads();
    for (int hh = w; hh < 64; hh += 4) {
        int m = idxs[hh];
        float2 v = *reinterpret_cast<const float2*>(
            emb + ((size_t)n * M_EMB + m) * D_EMB + lane * 2);
        q[hh][lane * 2]     = v.x;
        q[hh][lane * 2 + 1] = v.y;
    }
    __syncthreads();

    size_t base = ((size_t)b * N_CB + n) * (D_EMB * H_LAT);
    int h4 = (t & 15) * 4;
    float s = 0.f;
    #pragma unroll
    for (int p = 0; p < 8; p++) {      /* d = p*16 + (t>>4) in [0,128) */
        int d = p * 16 + (t >> 4);
        float4 xv = *reinterpret_cast<const float4*>(x + base + (size_t)d * H_LAT + h4);
        float4 qv = make_float4(q[h4][d], q[h4 + 1][d], q[h4 + 2][d], q[h4 + 3][d]);
        *reinterpret_cast<float4*>(out + base + (size_t)d * H_LAT + h4) = qv;
        float d0 = xv.x - qv.x, d1 = xv.y - qv.y, d2 = xv.z - qv.z, d3 = xv.w - qv.w;
        s += d0 * d0 + d1 * d1 + d2 * d2 + d3 * d3;
    }
    #pragma unroll
    for (int off = 32; off; off >>= 1) s += __shfl_down(s, off);
    if (lane == 0) wsum[w] = s;
    __syncthreads();
    if (t == 0) atomicAdd(lossacc, wsum[0] + wsum[1] + wsum[2] + wsum[3]);
}

/* entropy / perplexity + final loss. 1 block. */
__global__ void finish_kernel(const int* __restrict__ counts,
                              const float* __restrict__ lossacc,
                              float* __restrict__ out)
{
    __shared__ float red[16];
    int t = threadIdx.x;
    float entsum = 0.f, pplsum = 0.f;
    for (int n = 0; n < N_CB; n++) {
        float p = counts[n * M_EMB + t] * (1.f / L_PER);
        float s = p * logf(p + 1e-10f);
        #pragma unroll
        for (int off = 32; off; off >>= 1) s += __shfl_down(s, off);
        int lane = t & 63, w = t >> 6;
        if (lane == 0) red[w] = s;
        __syncthreads();
        if (t < 16) {
            float v = red[t];
            #pragma unroll
            for (int off = 8; off; off >>= 1) v += __shfl_down(v, off);
            if (t == 0) red[0] = v;
        }
        __syncthreads();
        float ent = -red[0];
        entsum += ent;
        pplsum += expf(ent);
        __syncthreads();
    }
    if (t == 0) {
        out[ENT_OFF]  = entsum * (1.f / N_CB);
        out[PPL_OFF]  = pplsum * (1.f / N_CB);
        out[LOSS_OFF] = 0.25f * (*lossacc) / (float)TOTAL_X;
    }
}

extern "C" void kernel_launch(void* const* d_in, const int* in_sizes, int n_in,
                              void* d_out, int out_size, void* d_ws, size_t ws_size,
                              hipStream_t stream)
{
    const float* x   = (const float*)d_in[0];
    const float* emb = (const float*)d_in[1];
    float* out = (float*)d_out;

    float* esq     = (float*)d_ws + WS_ESQ_OFF;
    int*   idx_ws  = (int*)d_ws + WS_IDX_OFF;
    int*   counts  = (int*)d_ws + WS_CNT_OFF;
    float* lossacc = (float*)d_ws + WS_LOSS_OFF;
    int*   paircnt = (int*)d_ws + WS_PCNT_OFF;

    unsigned int*       pairs  = (unsigned int*)out;
    unsigned long long* rowmin = (unsigned long long*)(out + OUT_RMIN_F);
    char*               ebf    = (char*)(out + OUT_EBF_F);

    hipLaunchKernelGGL(init_ws, dim3(512), dim3(256), 0, stream,
                       counts, lossacc, paircnt, rowmin);
    hipLaunchKernelGGL(esq_kernel, dim3(2048), dim3(256), 0, stream, emb, esq);
    hipLaunchKernelGGL(econv_kernel, dim3(64), dim3(256), 0, stream, emb, ebf);
    hipLaunchKernelGGL(vq_mfma_kernel, dim3(1024), dim3(256), 0, stream,
                       x, ebf, esq, idx_ws, counts, paircnt, pairs, out);
    hipLaunchKernelGGL(pair_np_kernel, dim3(1024), dim3(256), 0, stream,
                       x, emb, esq, paircnt, pairs, rowmin);
    hipLaunchKernelGGL(apply_fix_kernel, dim3(512), dim3(256), 0, stream,
                       rowmin, idx_ws, counts, out);
    hipLaunchKernelGGL(scatter_loss_kernel, dim3(2048), dim3(256), 0, stream,
                       x, emb, idx_ws, out, lossacc);
    hipLaunchKernelGGL(finish_kernel, dim3(1), dim3(1024), 0, stream,
                       counts, lossacc, out);
}

// Round 7
// 534.198 us; speedup vs baseline: 3.7334x; 3.7334x over previous
//
#include <hip/hip_runtime.h>
#include <hip/hip_bf16.h>
#include <math.h>

#define N_CB   8
#define M_EMB  1024
#define D_EMB  128
#define H_LAT  64
#define B_SZ   256
#define L_PER  (B_SZ * H_LAT)
#define TOTAL_X (B_SZ * N_CB * D_EMB * H_LAT)
#define NROW   (N_CB * L_PER)              /* 131072 rows */

/* d_out layout (floats): [z_q | loss | entropy | perplexity | indices] */
#define LOSS_OFF (TOTAL_X)
#define ENT_OFF  (TOTAL_X + 1)
#define PPL_OFF  (TOTAL_X + 2)
#define IDX_OFF  (TOTAL_X + 3)

/* ws layout (4-byte units) — <= 721KB proven-safe */
#define WS_ESQ_OFF   0
#define WS_IDX_OFF   8192
#define WS_CNT_OFF   139264
#define WS_LOSS_OFF  147456
#define WS_PCNT_OFF  147457

/* scratch in d_out's z_q region (overwritten by scatter afterwards):
 * pairs u64 [0, 3M floats) | rowmin u64 [3.0M, 3.27M) | rowthr [3.3M, 3.44M) */
#define OUT_PAIRS_F  0
#define PAIR_CAP     1500000
#define OUT_RMIN_F   3000000
#define OUT_THR_F    3300000

#define TAU2 2e-3f
#define LCAP 1280

typedef __attribute__((ext_vector_type(8))) short short8;
typedef __attribute__((ext_vector_type(4))) float floatx4;

__device__ __forceinline__ unsigned int bf16rn(float f) {
    unsigned int u = __float_as_uint(f);
    return (u + 0x7FFFu + ((u >> 16) & 1u)) >> 16;   /* RNE, NaN-free inputs */
}
/* order-preserving float->u32 (handles negatives) */
__device__ __forceinline__ unsigned int fkey(float f) {
    unsigned int u = __float_as_uint(f);
    return (u & 0x80000000u) ? ~u : (u | 0x80000000u);
}

__global__ void init_ws(int* __restrict__ counts, float* __restrict__ lossacc,
                        int* __restrict__ paircnt,
                        unsigned long long* __restrict__ rowmin) {
    int t = blockIdx.x * 256 + threadIdx.x;
    if (t < NROW) rowmin[t] = ~0ull;
    if (t < N_CB * M_EMB) counts[t] = 0;
    if (t == 0) { *lossacc = 0.f; *paircnt = 0; }
}

/* one wave per embedding row: e_sq[n,m] = sum_d e^2 */
__global__ void esq_kernel(const float* __restrict__ e, float* __restrict__ esq) {
    int wave = (blockIdx.x * blockDim.x + threadIdx.x) >> 6;
    int lane = threadIdx.x & 63;
    if (wave >= N_CB * M_EMB) return;
    float2 v = reinterpret_cast<const float2*>(e + (size_t)wave * D_EMB)[lane];
    float s = v.x * v.x + v.y * v.y;
    #pragma unroll
    for (int off = 32; off; off >>= 1) s += __shfl_down(s, off);
    if (lane == 0) esq[wave] = s;
}

/* Single-sweep MFMA distance-GEMM + argmin + candidate emission.
 * grid = 8 n x 128 ltiles = 1024 blocks, 256 thr. Block: 128 rows x 1024 m.
 * Per mc-chunk: MFMA -> key update -> 16-lane in-place reduce -> emit all
 * dist < runmin+TAU2 into an LDS buffer. One global atomic per block flushes. */
__launch_bounds__(256, 2)
__global__ void vq_mfma_kernel(const float* __restrict__ x,
                               const float* __restrict__ emb,
                               const float* __restrict__ esq,
                               int*  __restrict__ idx_ws,
                               int*  __restrict__ counts,
                               int*  __restrict__ paircnt,
                               unsigned long long* pairs,     /* aliases out */
                               float* rowthr,                 /* aliases out */
                               float* out)
{
    __shared__ __align__(16) char smem[65536];   /* As 32KB | Bs 32KB */
    __shared__ unsigned long long lds_pairs[LCAP];
    __shared__ int lds_cnt;
    __shared__ int gbase;
    const int bid = blockIdx.x;
    const int n = bid >> 7, ltile = bid & 127;
    const int b0 = ltile * 2;
    const int t = threadIdx.x;
    const int l = t & 63, w = t >> 6;
    const int wr = w >> 1, wc = w & 1;

    if (t == 0) lds_cnt = 0;

    /* ---- stage A: x tile 128 rows x 128 k -> bf16 swizzled ---- */
    {
        int r = t & 127, kh = t >> 7;
        int bb = r >> 6, h = r & 63;
        const float* gx = x + ((size_t)(b0 + bb) * N_CB + n) * (D_EMB * H_LAT) + h;
        int swz = (r & 15) << 4;
        char* arow = smem + r * 256;
        #pragma unroll 4
        for (int i = 0; i < 64; i += 4) {
            int k = kh * 64 + i;
            float f0 = gx[(size_t)(k + 0) * H_LAT];
            float f1 = gx[(size_t)(k + 1) * H_LAT];
            float f2 = gx[(size_t)(k + 2) * H_LAT];
            float f3 = gx[(size_t)(k + 3) * H_LAT];
            unsigned int p0 = bf16rn(f0) | (bf16rn(f1) << 16);
            unsigned int p1 = bf16rn(f2) | (bf16rn(f3) << 16);
            *reinterpret_cast<uint2*>(arow + ((2 * k) ^ swz)) = make_uint2(p0, p1);
        }
    }

    float m1[16];
    #pragma unroll
    for (int i = 0; i < 16; i++) m1[i] = INFINITY;

    const float* ebase = emb + (size_t)n * M_EMB * D_EMB;
    const float* esq_n = esq + n * M_EMB;

    const int lx = l & 15;
    const int rbase = wr * 64 + lx;
    const int cbase = wc * 64 + lx;
    const int kb_lane = (l >> 4) * 16;
    const int swzl = lx << 4;
    /* global row id base: rid(s) = ridb + (s>>2)*16 + (s&3) */
    const int ridb = n * L_PER + (b0 + wr) * H_LAT + (l >> 4) * 4;

    const int tk = t & 31;                 /* B-stage: float4 chunk along k */
    const int trow = t >> 5;               /* B-stage: row mod 8 */

    for (int mc = 0; mc < 8; ++mc) {
        __syncthreads();                   /* prior consumers done / A staged */
        {   /* stage Bs: 128 m-rows x 128 k from f32 emb, convert + swizzle */
            #pragma unroll
            for (int rr = 0; rr < 16; ++rr) {
                int mrow = rr * 8 + trow;
                float4 v = *reinterpret_cast<const float4*>(
                    ebase + (size_t)(mc * 128 + mrow) * D_EMB + tk * 4);
                unsigned int p0 = bf16rn(v.x) | (bf16rn(v.y) << 16);
                unsigned int p1 = bf16rn(v.z) | (bf16rn(v.w) << 16);
                int swz = (mrow & 15) << 4;
                *reinterpret_cast<uint2*>(
                    smem + 32768 + mrow * 256 + ((tk * 8) ^ swz)) = make_uint2(p0, p1);
            }
        }
        __syncthreads();

        floatx4 acc[4][4];
        #pragma unroll
        for (int i = 0; i < 4; i++)
            #pragma unroll
            for (int j = 0; j < 4; j++)
                acc[i][j] = (floatx4){0.f, 0.f, 0.f, 0.f};

        #pragma unroll
        for (int kc = 0; kc < 4; ++kc) {
            const int kx = (kc * 64 + kb_lane) ^ swzl;
            short8 a[4], b[4];
            #pragma unroll
            for (int i = 0; i < 4; i++)
                a[i] = *reinterpret_cast<const short8*>(smem + (rbase + i * 16) * 256 + kx);
            #pragma unroll
            for (int j = 0; j < 4; j++)
                b[j] = *reinterpret_cast<const short8*>(smem + 32768 + (cbase + j * 16) * 256 + kx);
            #pragma unroll
            for (int i = 0; i < 4; i++)
                #pragma unroll
                for (int j = 0; j < 4; j++)
                    acc[i][j] = __builtin_amdgcn_mfma_f32_16x16x32_bf16(a[i], b[j], acc[i][j], 0, 0, 0);
        }

        /* keys + running min (m embedded in low 10 mantissa bits) */
        const int mb = mc * 128 + cbase;
        float eqv[4];
        #pragma unroll
        for (int j = 0; j < 4; j++) eqv[j] = esq_n[mb + j * 16];
        #pragma unroll
        for (int j = 0; j < 4; j++) {
            unsigned int midx = (unsigned int)(mb + j * 16);
            #pragma unroll
            for (int i = 0; i < 4; i++)
                #pragma unroll
                for (int r = 0; r < 4; r++) {
                    float dist = fmaf(-2.f, acc[i][j][r], eqv[j]);
                    float key = __uint_as_float((__float_as_uint(dist) & 0xFFFFFC00u) | midx);
                    int s = i * 4 + r;
                    m1[s] = fminf(m1[s], key);
                }
        }
        /* in-place 16-lane group reduce: m1 becomes row-running-min */
        #pragma unroll
        for (int s = 0; s < 16; s++) {
            float v1 = m1[s];
            #pragma unroll
            for (int off = 1; off < 16; off <<= 1) v1 = fminf(v1, __shfl_xor(v1, off));
            m1[s] = v1;
        }
        /* emission: all dist < runmin + TAU2 (superset of final window) */
        #pragma unroll
        for (int j = 0; j < 4; j++) {
            #pragma unroll
            for (int i = 0; i < 4; i++)
                #pragma unroll
                for (int r = 0; r < 4; r++) {
                    float dist = fmaf(-2.f, acc[i][j][r], eqv[j]);
                    int s = i * 4 + r;
                    if (dist < m1[s] + TAU2) {
                        unsigned long long pr =
                            ((unsigned long long)__float_as_uint(dist) << 32)
                          | ((unsigned long long)(unsigned)(ridb + i * 16 + r) << 10)
                          | (unsigned long long)(unsigned)(mb + j * 16);
                        int lp = atomicAdd(&lds_cnt, 1);
                        if (lp < LCAP) lds_pairs[lp] = pr;
                        else {           /* rare overflow fallback */
                            int gp = atomicAdd(paircnt, 1);
                            if (gp < PAIR_CAP) pairs[gp] = pr;
                        }
                    }
                }
        }
    }

    /* final cross-wave winner */
    __syncthreads();                       /* MFMA LDS reads done; reuse smem */
    float* red = reinterpret_cast<float*>(smem);   /* [128 rows][2 wc] */
    if (lx == 0) {
        #pragma unroll
        for (int i = 0; i < 4; i++)
            #pragma unroll
            for (int r = 0; r < 4; r++) {
                int row = wr * 64 + i * 16 + (l >> 4) * 4 + r;
                red[row * 2 + wc] = m1[i * 4 + r];
            }
    }
    __syncthreads();
    if (wc == 0) {
        int row = wr * 64 + l;
        float v1 = fminf(red[row * 2 + 0], red[row * 2 + 1]);
        int i1 = (int)(__float_as_uint(v1) & 1023u);
        int b = b0 + (row >> 6), h = row & 63;
        int lidx = b * H_LAT + h;
        int rid = n * L_PER + lidx;
        idx_ws[rid] = i1;
        atomicAdd(&counts[n * M_EMB + i1], 1);
        out[IDX_OFF + (b * N_CB + n) * H_LAT + h] = (float)i1;
        rowthr[rid] = v1 + TAU2;
    }

    /* flush LDS pair buffer: ONE global atomic per block */
    __syncthreads();
    if (t == 0) gbase = atomicAdd(paircnt, min(lds_cnt, LCAP));
    __syncthreads();
    int cnt = min(lds_cnt, LCAP);
    for (int i = t; i < cnt; i += 256) {
        int gp = gbase + i;
        if (gp < PAIR_CAP) pairs[gp] = lds_pairs[i];
    }
}

/* np-fp32-semantics distance for surviving pairs; atomicMin into per-row u64.
 * Filter against rowthr (final bf16 min + TAU2) before the heavy work. */
__global__ void pair_np_kernel(const float* __restrict__ x,
                               const float* __restrict__ emb,
                               const float* __restrict__ esq,
                               const int* __restrict__ paircnt,
                               const unsigned long long* __restrict__ pairs,
                               const float* __restrict__ rowthr,
                               unsigned long long* __restrict__ rowmin)
{
    int np = *paircnt;
    if (np > PAIR_CAP) np = PAIR_CAP;
    for (int p = blockIdx.x * blockDim.x + threadIdx.x; p < np;
         p += gridDim.x * blockDim.x) {
        unsigned long long pr = pairs[p];
        float dist_b = __uint_as_float((unsigned int)(pr >> 32));
        int m   = (int)(pr & 1023u);
        int rid = (int)((pr >> 10) & 0x1FFFFu);
        if (!(dist_b < rowthr[rid])) continue;
        int n = rid >> 14, lrow = rid & (L_PER - 1);
        int b = lrow >> 6, h = lrow & 63;
        const float* xb = x + ((size_t)b * N_CB + n) * (D_EMB * H_LAT) + h;
        float xr[128];
        #pragma unroll
        for (int d = 0; d < 128; d++) xr[d] = xb[(size_t)d * H_LAT];
        double s = 0.0;
        #pragma unroll
        for (int d = 0; d < 128; d++) s += (double)xr[d] * xr[d];
        float xsq = (float)s;

        const float* er = emb + ((size_t)n * M_EMB + m) * D_EMB;
        float a0 = 0.f, a1 = 0.f, a2 = 0.f, a3 = 0.f;
        #pragma unroll 8
        for (int i = 0; i < 128; i += 4) {
            a0 = __fadd_rn(a0, __fmul_rn(xr[i + 0], er[i + 0]));
            a1 = __fadd_rn(a1, __fmul_rn(xr[i + 1], er[i + 1]));
            a2 = __fadd_rn(a2, __fmul_rn(xr[i + 2], er[i + 2]));
            a3 = __fadd_rn(a3, __fmul_rn(xr[i + 3], er[i + 3]));
        }
        float cr   = __fadd_rn(__fadd_rn(a0, a1), __fadd_rn(a2, a3));
        float t1   = __fadd_rn(esq[n * M_EMB + m], xsq);
        float dist = __fadd_rn(t1, __fmul_rn(-2.f, cr));
        unsigned long long key =
            ((unsigned long long)fkey(dist) << 32) | (unsigned long long)m;
        atomicMin(&rowmin[rid], key);
    }
}

/* apply np-exact winner per row */
__global__ void apply_fix_kernel(const unsigned long long* __restrict__ rowmin,
                                 int* __restrict__ idx_ws,
                                 int* __restrict__ counts,
                                 float* __restrict__ out)
{
    int rid = blockIdx.x * 256 + threadIdx.x;
    if (rid >= NROW) return;
    unsigned long long key = rowmin[rid];
    if (key == ~0ull) return;
    int m = (int)(key & 1023u);
    int old = idx_ws[rid];
    if (old != m) {
        int n = rid >> 14, lrow = rid & (L_PER - 1);
        idx_ws[rid] = m;
        atomicSub(&counts[n * M_EMB + old], 1);
        atomicAdd(&counts[n * M_EMB + m], 1);
        int b = lrow >> 6, h = lrow & 63;
        out[IDX_OFF + (b * N_CB + n) * H_LAT + h] = (float)m;
    }
}

/* z_q scatter + commitment loss. Block per (b,n). */
__global__ void scatter_loss_kernel(const float* __restrict__ x,
                                    const float* __restrict__ emb,
                                    const int* __restrict__ idx_ws,
                                    float* __restrict__ out,
                                    float* __restrict__ lossacc)
{
    __shared__ float q[64][129];
    __shared__ int   idxs[64];
    __shared__ float wsum[4];
    int bid = blockIdx.x;
    int n = bid & 7, b = bid >> 3;
    int t = threadIdx.x, lane = t & 63, w = t >> 6;

    if (t < 64) idxs[t] = idx_ws[n * L_PER + b * H_LAT + t];
    __syncthreads();
    for (int hh = w; hh < 64; hh += 4) {
        int m = idxs[hh];
        float2 v = *reinterpret_cast<const float2*>(
            emb + ((size_t)n * M_EMB + m) * D_EMB + lane * 2);
        q[hh][lane * 2]     = v.x;
        q[hh][lane * 2 + 1] = v.y;
    }
    __syncthreads();

    size_t base = ((size_t)b * N_CB + n) * (D_EMB * H_LAT);
    int h4 = (t & 15) * 4;
    float s = 0.f;
    #pragma unroll
    for (int p = 0; p < 8; p++) {
        int d = p * 16 + (t >> 4);
        float4 xv = *reinterpret_cast<const float4*>(x + base + (size_t)d * H_LAT + h4);
        float4 qv = make_float4(q[h4][d], q[h4 + 1][d], q[h4 + 2][d], q[h4 + 3][d]);
        *reinterpret_cast<float4*>(out + base + (size_t)d * H_LAT + h4) = qv;
        float d0 = xv.x - qv.x, d1 = xv.y - qv.y, d2 = xv.z - qv.z, d3 = xv.w - qv.w;
        s += d0 * d0 + d1 * d1 + d2 * d2 + d3 * d3;
    }
    #pragma unroll
    for (int off = 32; off; off >>= 1) s += __shfl_down(s, off);
    if (lane == 0) wsum[w] = s;
    __syncthreads();
    if (t == 0) atomicAdd(lossacc, wsum[0] + wsum[1] + wsum[2] + wsum[3]);
}

/* entropy / perplexity + final loss. 1 block. */
__global__ void finish_kernel(const int* __restrict__ counts,
                              const float* __restrict__ lossacc,
                              float* __restrict__ out)
{
    __shared__ float red[16];
    int t = threadIdx.x;
    float entsum = 0.f, pplsum = 0.f;
    for (int n = 0; n < N_CB; n++) {
        float p = counts[n * M_EMB + t] * (1.f / L_PER);
        float s = p * logf(p + 1e-10f);
        #pragma unroll
        for (int off = 32; off; off >>= 1) s += __shfl_down(s, off);
        int lane = t & 63, w = t >> 6;
        if (lane == 0) red[w] = s;
        __syncthreads();
        if (t < 16) {
            float v = red[t];
            #pragma unroll
            for (int off = 8; off; off >>= 1) v += __shfl_down(v, off);
            if (t == 0) red[0] = v;
        }
        __syncthreads();
        float ent = -red[0];
        entsum += ent;
        pplsum += expf(ent);
        __syncthreads();
    }
    if (t == 0) {
        out[ENT_OFF]  = entsum * (1.f / N_CB);
        out[PPL_OFF]  = pplsum * (1.f / N_CB);
        out[LOSS_OFF] = 0.25f * (*lossacc) / (float)TOTAL_X;
    }
}

extern "C" void kernel_launch(void* const* d_in, const int* in_sizes, int n_in,
                              void* d_out, int out_size, void* d_ws, size_t ws_size,
                              hipStream_t stream)
{
    const float* x   = (const float*)d_in[0];
    const float* emb = (const float*)d_in[1];
    float* out = (float*)d_out;

    float* esq     = (float*)d_ws + WS_ESQ_OFF;
    int*   idx_ws  = (int*)d_ws + WS_IDX_OFF;
    int*   counts  = (int*)d_ws + WS_CNT_OFF;
    float* lossacc = (float*)d_ws + WS_LOSS_OFF;
    int*   paircnt = (int*)d_ws + WS_PCNT_OFF;

    unsigned long long* pairs  = (unsigned long long*)(out + OUT_PAIRS_F);
    unsigned long long* rowmin = (unsigned long long*)(out + OUT_RMIN_F);
    float*              rowthr = out + OUT_THR_F;

    hipLaunchKernelGGL(init_ws, dim3(512), dim3(256), 0, stream,
                       counts, lossacc, paircnt, rowmin);
    hipLaunchKernelGGL(esq_kernel, dim3(2048), dim3(256), 0, stream, emb, esq);
    hipLaunchKernelGGL(vq_mfma_kernel, dim3(1024), dim3(256), 0, stream,
                       x, emb, esq, idx_ws, counts, paircnt, pairs, rowthr, out);
    hipLaunchKernelGGL(pair_np_kernel, dim3(2048), dim3(256), 0, stream,
                       x, emb, esq, paircnt, pairs, rowthr, rowmin);
    hipLaunchKernelGGL(apply_fix_kernel, dim3(512), dim3(256), 0, stream,
                       rowmin, idx_ws, counts, out);
    hipLaunchKernelGGL(scatter_loss_kernel, dim3(2048), dim3(256), 0, stream,
                       x, emb, idx_ws, out, lossacc);
    hipLaunchKernelGGL(finish_kernel, dim3(1), dim3(1024), 0, stream,
                       counts, lossacc, out);
}

// Round 9
// 344.108 us; speedup vs baseline: 5.7958x; 1.5524x over previous
//
#include <hip/hip_runtime.h>
#include <hip/hip_bf16.h>
#include <math.h>

#define N_CB   8
#define M_EMB  1024
#define D_EMB  128
#define H_LAT  64
#define B_SZ   256
#define L_PER  (B_SZ * H_LAT)
#define TOTAL_X (B_SZ * N_CB * D_EMB * H_LAT)
#define NROW   (N_CB * L_PER)              /* 131072 rows */

/* d_out layout (floats): [z_q | loss | entropy | perplexity | indices] */
#define LOSS_OFF (TOTAL_X)
#define ENT_OFF  (TOTAL_X + 1)
#define PPL_OFF  (TOTAL_X + 2)
#define IDX_OFF  (TOTAL_X + 3)

/* ws layout (4-byte units) — <= 721KB proven-safe */
#define WS_ESQ_OFF   0
#define WS_IDX_OFF   8192
#define WS_CNT_OFF   139264
#define WS_LOSS_OFF  147456
#define WS_PCNT_OFF  147457

/* scratch in d_out's z_q region (overwritten by scatter afterwards):
 * pairs u64 [0,3M) | rowmin u64 [3.0M,3.27M) | rowthr [3.3M,3.44M) | xsq [3.5M,3.64M) */
#define OUT_PAIRS_F  0
#define PAIR_CAP     1500000
#define OUT_RMIN_F   3000000
#define OUT_THR_F    3300000
#define OUT_XSQ_F    3500000

#define TAU2 2e-3f
#define LCAP 1280

typedef __attribute__((ext_vector_type(8))) short short8;
typedef __attribute__((ext_vector_type(4))) float floatx4;

__device__ __forceinline__ unsigned int bf16rn(float f) {
    unsigned int u = __float_as_uint(f);
    return (u + 0x7FFFu + ((u >> 16) & 1u)) >> 16;   /* RNE, NaN-free inputs */
}
/* order-preserving float->u32 (handles negatives) */
__device__ __forceinline__ unsigned int fkey(float f) {
    unsigned int u = __float_as_uint(f);
    return (u & 0x80000000u) ? ~u : (u | 0x80000000u);
}

__global__ void init_ws(int* __restrict__ counts, float* __restrict__ lossacc,
                        int* __restrict__ paircnt,
                        unsigned long long* __restrict__ rowmin) {
    int t = blockIdx.x * 256 + threadIdx.x;
    if (t < NROW) rowmin[t] = ~0ull;
    if (t < N_CB * M_EMB) counts[t] = 0;
    if (t == 0) { *lossacc = 0.f; *paircnt = 0; }
}

/* one wave per embedding row: e_sq[n,m] = sum_d e^2 */
__global__ void esq_kernel(const float* __restrict__ e, float* __restrict__ esq) {
    int wave = (blockIdx.x * blockDim.x + threadIdx.x) >> 6;
    int lane = threadIdx.x & 63;
    if (wave >= N_CB * M_EMB) return;
    float2 v = reinterpret_cast<const float2*>(e + (size_t)wave * D_EMB)[lane];
    float s = v.x * v.x + v.y * v.y;
    #pragma unroll
    for (int off = 32; off; off >>= 1) s += __shfl_down(s, off);
    if (lane == 0) esq[wave] = s;
}

/* per-row x_sq (fp64 acc -> fp32). Block=64 thr (one wave) per (b,n);
 * lane=h -> consecutive addresses each d-iteration: fully coalesced. */
__global__ void xsq_kernel(const float* __restrict__ x, float* __restrict__ rowxsq) {
    int blk = blockIdx.x;              /* b*8 + n */
    int b = blk >> 3, n = blk & 7;
    int h = threadIdx.x;
    const float* xb = x + ((size_t)b * N_CB + n) * (D_EMB * H_LAT) + h;
    double s = 0.0;
    #pragma unroll 16
    for (int d = 0; d < 128; d++) {
        double v = (double)xb[(size_t)d * H_LAT];
        s += v * v;
    }
    rowxsq[n * L_PER + b * H_LAT + h] = (float)s;
}

/* Single-sweep MFMA distance-GEMM + argmin + candidate emission.
 * grid = 8 n x 128 ltiles = 1024 blocks, 256 thr. Block: 128 rows x 1024 m.
 * Per mc-chunk: MFMA -> key update -> 16-lane in-place reduce -> emit all
 * dist < runmin+TAU2 into an LDS buffer. One global atomic per block flushes. */
__launch_bounds__(256, 2)
__global__ void vq_mfma_kernel(const float* __restrict__ x,
                               const float* __restrict__ emb,
                               const float* __restrict__ esq,
                               int*  __restrict__ idx_ws,
                               int*  __restrict__ counts,
                               int*  __restrict__ paircnt,
                               unsigned long long* pairs,     /* aliases out */
                               float* rowthr,                 /* aliases out */
                               float* out)
{
    __shared__ __align__(16) char smem[65536];   /* As 32KB | Bs 32KB */
    __shared__ unsigned long long lds_pairs[LCAP];
    __shared__ int lds_cnt;
    __shared__ int gbase;
    const int bid = blockIdx.x;
    const int n = bid >> 7, ltile = bid & 127;
    const int b0 = ltile * 2;
    const int t = threadIdx.x;
    const int l = t & 63, w = t >> 6;
    const int wr = w >> 1, wc = w & 1;

    if (t == 0) lds_cnt = 0;

    /* ---- stage A: x tile 128 rows x 128 k -> bf16 swizzled ---- */
    {
        int r = t & 127, kh = t >> 7;
        int bb = r >> 6, h = r & 63;
        const float* gx = x + ((size_t)(b0 + bb) * N_CB + n) * (D_EMB * H_LAT) + h;
        int swz = (r & 15) << 4;
        char* arow = smem + r * 256;
        #pragma unroll 4
        for (int i = 0; i < 64; i += 4) {
            int k = kh * 64 + i;
            float f0 = gx[(size_t)(k + 0) * H_LAT];
            float f1 = gx[(size_t)(k + 1) * H_LAT];
            float f2 = gx[(size_t)(k + 2) * H_LAT];
            float f3 = gx[(size_t)(k + 3) * H_LAT];
            unsigned int p0 = bf16rn(f0) | (bf16rn(f1) << 16);
            unsigned int p1 = bf16rn(f2) | (bf16rn(f3) << 16);
            *reinterpret_cast<uint2*>(arow + ((2 * k) ^ swz)) = make_uint2(p0, p1);
        }
    }

    float m1[16];
    #pragma unroll
    for (int i = 0; i < 16; i++) m1[i] = INFINITY;

    const float* ebase = emb + (size_t)n * M_EMB * D_EMB;
    const float* esq_n = esq + n * M_EMB;

    const int lx = l & 15;
    const int rbase = wr * 64 + lx;
    const int cbase = wc * 64 + lx;
    const int kb_lane = (l >> 4) * 16;
    const int swzl = lx << 4;
    /* global row id base: rid(s) = ridb + (s>>2)*16 + (s&3) */
    const int ridb = n * L_PER + (b0 + wr) * H_LAT + (l >> 4) * 4;

    const int tk = t & 31;                 /* B-stage: float4 chunk along k */
    const int trow = t >> 5;               /* B-stage: row mod 8 */

    for (int mc = 0; mc < 8; ++mc) {
        __syncthreads();                   /* prior consumers done / A staged */
        {   /* stage Bs: 128 m-rows x 128 k from f32 emb, convert + swizzle */
            #pragma unroll
            for (int rr = 0; rr < 16; ++rr) {
                int mrow = rr * 8 + trow;
                float4 v = *reinterpret_cast<const float4*>(
                    ebase + (size_t)(mc * 128 + mrow) * D_EMB + tk * 4);
                unsigned int p0 = bf16rn(v.x) | (bf16rn(v.y) << 16);
                unsigned int p1 = bf16rn(v.z) | (bf16rn(v.w) << 16);
                int swz = (mrow & 15) << 4;
                *reinterpret_cast<uint2*>(
                    smem + 32768 + mrow * 256 + ((tk * 8) ^ swz)) = make_uint2(p0, p1);
            }
        }
        __syncthreads();

        floatx4 acc[4][4];
        #pragma unroll
        for (int i = 0; i < 4; i++)
            #pragma unroll
            for (int j = 0; j < 4; j++)
                acc[i][j] = (floatx4){0.f, 0.f, 0.f, 0.f};

        #pragma unroll
        for (int kc = 0; kc < 4; ++kc) {
            const int kx = (kc * 64 + kb_lane) ^ swzl;
            short8 a[4], b[4];
            #pragma unroll
            for (int i = 0; i < 4; i++)
                a[i] = *reinterpret_cast<const short8*>(smem + (rbase + i * 16) * 256 + kx);
            #pragma unroll
            for (int j = 0; j < 4; j++)
                b[j] = *reinterpret_cast<const short8*>(smem + 32768 + (cbase + j * 16) * 256 + kx);
            #pragma unroll
            for (int i = 0; i < 4; i++)
                #pragma unroll
                for (int j = 0; j < 4; j++)
                    acc[i][j] = __builtin_amdgcn_mfma_f32_16x16x32_bf16(a[i], b[j], acc[i][j], 0, 0, 0);
        }

        /* keys + running min (m embedded in low 10 mantissa bits) */
        const int mb = mc * 128 + cbase;
        float eqv[4];
        #pragma unroll
        for (int j = 0; j < 4; j++) eqv[j] = esq_n[mb + j * 16];
        #pragma unroll
        for (int j = 0; j < 4; j++) {
            unsigned int midx = (unsigned int)(mb + j * 16);
            #pragma unroll
            for (int i = 0; i < 4; i++)
                #pragma unroll
                for (int r = 0; r < 4; r++) {
                    float dist = fmaf(-2.f, acc[i][j][r], eqv[j]);
                    float key = __uint_as_float((__float_as_uint(dist) & 0xFFFFFC00u) | midx);
                    int s = i * 4 + r;
                    m1[s] = fminf(m1[s], key);
                }
        }
        /* in-place 16-lane group reduce: m1 becomes row-running-min */
        #pragma unroll
        for (int s = 0; s < 16; s++) {
            float v1 = m1[s];
            #pragma unroll
            for (int off = 1; off < 16; off <<= 1) v1 = fminf(v1, __shfl_xor(v1, off));
            m1[s] = v1;
        }
        /* emission: all dist < runmin + TAU2 (superset of final window) */
        #pragma unroll
        for (int j = 0; j < 4; j++) {
            #pragma unroll
            for (int i = 0; i < 4; i++)
                #pragma unroll
                for (int r = 0; r < 4; r++) {
                    float dist = fmaf(-2.f, acc[i][j][r], eqv[j]);
                    int s = i * 4 + r;
                    if (dist < m1[s] + TAU2) {
                        unsigned long long pr =
                            ((unsigned long long)__float_as_uint(dist) << 32)
                          | ((unsigned long long)(unsigned)(ridb + i * 16 + r) << 10)
                          | (unsigned long long)(unsigned)(mb + j * 16);
                        int lp = atomicAdd(&lds_cnt, 1);
                        if (lp < LCAP) lds_pairs[lp] = pr;
                        else {           /* rare overflow fallback */
                            int gp = atomicAdd(paircnt, 1);
                            if (gp < PAIR_CAP) pairs[gp] = pr;
                        }
                    }
                }
        }
    }

    /* final cross-wave winner */
    __syncthreads();                       /* MFMA LDS reads done; reuse smem */
    float* red = reinterpret_cast<float*>(smem);   /* [128 rows][2 wc] */
    if (lx == 0) {
        #pragma unroll
        for (int i = 0; i < 4; i++)
            #pragma unroll
            for (int r = 0; r < 4; r++) {
                int row = wr * 64 + i * 16 + (l >> 4) * 4 + r;
                red[row * 2 + wc] = m1[i * 4 + r];
            }
    }
    __syncthreads();
    if (wc == 0) {
        int row = wr * 64 + l;
        float v1 = fminf(red[row * 2 + 0], red[row * 2 + 1]);
        int i1 = (int)(__float_as_uint(v1) & 1023u);
        int b = b0 + (row >> 6), h = row & 63;
        int lidx = b * H_LAT + h;
        int rid = n * L_PER + lidx;
        idx_ws[rid] = i1;
        atomicAdd(&counts[n * M_EMB + i1], 1);
        out[IDX_OFF + (b * N_CB + n) * H_LAT + h] = (float)i1;
        rowthr[rid] = v1 + TAU2;
    }

    /* flush LDS pair buffer: ONE global atomic per block */
    __syncthreads();
    if (t == 0) gbase = atomicAdd(paircnt, min(lds_cnt, LCAP));
    __syncthreads();
    int cnt = min(lds_cnt, LCAP);
    for (int i = t; i < cnt; i += 256) {
        int gp = gbase + i;
        if (gp < PAIR_CAP) pairs[gp] = lds_pairs[i];
    }
}

/* np-fp32-semantics distance for surviving pairs; atomicMin into per-row u64.
 * Filter against rowthr first. No per-thread arrays: x read directly from
 * global (L2/L3-resident) inside the strict-np loop; xsq precomputed. */
__global__ void pair_np_kernel(const float* __restrict__ x,
                               const float* __restrict__ emb,
                               const float* __restrict__ esq,
                               const int* __restrict__ paircnt,
                               const unsigned long long* __restrict__ pairs,
                               const float* __restrict__ rowthr,
                               const float* __restrict__ rowxsq,
                               unsigned long long* __restrict__ rowmin)
{
    int np = *paircnt;
    if (np > PAIR_CAP) np = PAIR_CAP;
    for (int p = blockIdx.x * blockDim.x + threadIdx.x; p < np;
         p += gridDim.x * blockDim.x) {
        unsigned long long pr = pairs[p];
        float dist_b = __uint_as_float((unsigned int)(pr >> 32));
        int m   = (int)(pr & 1023u);
        int rid = (int)((pr >> 10) & 0x1FFFFu);
        if (!(dist_b < rowthr[rid])) continue;
        int n = rid >> 14, lrow = rid & (L_PER - 1);
        int b = lrow >> 6, h = lrow & 63;
        const float* xb = x + ((size_t)b * N_CB + n) * (D_EMB * H_LAT) + h;
        const float* er = emb + ((size_t)n * M_EMB + m) * D_EMB;

        float a0 = 0.f, a1 = 0.f, a2 = 0.f, a3 = 0.f;
        #pragma unroll 8
        for (int i = 0; i < 128; i += 4) {
            a0 = __fadd_rn(a0, __fmul_rn(xb[(size_t)(i + 0) * H_LAT], er[i + 0]));
            a1 = __fadd_rn(a1, __fmul_rn(xb[(size_t)(i + 1) * H_LAT], er[i + 1]));
            a2 = __fadd_rn(a2, __fmul_rn(xb[(size_t)(i + 2) * H_LAT], er[i + 2]));
            a3 = __fadd_rn(a3, __fmul_rn(xb[(size_t)(i + 3) * H_LAT], er[i + 3]));
        }
        float cr   = __fadd_rn(__fadd_rn(a0, a1), __fadd_rn(a2, a3));
        float t1   = __fadd_rn(esq[n * M_EMB + m], rowxsq[rid]);
        float dist = __fadd_rn(t1, __fmul_rn(-2.f, cr));
        unsigned long long key =
            ((unsigned long long)fkey(dist) << 32) | (unsigned long long)m;
        atomicMin(&rowmin[rid], key);
    }
}

/* apply np-exact winner per row */
__global__ void apply_fix_kernel(const unsigned long long* __restrict__ rowmin,
                                 int* __restrict__ idx_ws,
                                 int* __restrict__ counts,
                                 float* __restrict__ out)
{
    int rid = blockIdx.x * 256 + threadIdx.x;
    if (rid >= NROW) return;
    unsigned long long key = rowmin[rid];
    if (key == ~0ull) return;
    int m = (int)(key & 1023u);
    int old = idx_ws[rid];
    if (old != m) {
        int n = rid >> 14, lrow = rid & (L_PER - 1);
        idx_ws[rid] = m;
        atomicSub(&counts[n * M_EMB + old], 1);
        atomicAdd(&counts[n * M_EMB + m], 1);
        int b = lrow >> 6, h = lrow & 63;
        out[IDX_OFF + (b * N_CB + n) * H_LAT + h] = (float)m;
    }
}

/* z_q scatter + commitment loss. Block per (b,n). */
__global__ void scatter_loss_kernel(const float* __restrict__ x,
                                    const float* __restrict__ emb,
                                    const int* __restrict__ idx_ws,
                                    float* __restrict__ out,
                                    float* __restrict__ lossacc)
{
    __shared__ float q[64][129];
    __shared__ int   idxs[64];
    __shared__ float wsum[4];
    int bid = blockIdx.x;
    int n = bid & 7, b = bid >> 3;
    int t = threadIdx.x, lane = t & 63, w = t >> 6;

    if (t < 64) idxs[t] = idx_ws[n * L_PER + b * H_LAT + t];
    __syncthreads();
    for (int hh = w; hh < 64; hh += 4) {
        int m = idxs[hh];
        float2 v = *reinterpret_cast<const float2*>(
            emb + ((size_t)n * M_EMB + m) * D_EMB + lane * 2);
        q[hh][lane * 2]     = v.x;
        q[hh][lane * 2 + 1] = v.y;
    }
    __syncthreads();

    size_t base = ((size_t)b * N_CB + n) * (D_EMB * H_LAT);
    int h4 = (t & 15) * 4;
    float s = 0.f;
    #pragma unroll
    for (int p = 0; p < 8; p++) {
        int d = p * 16 + (t >> 4);
        float4 xv = *reinterpret_cast<const float4*>(x + base + (size_t)d * H_LAT + h4);
        float4 qv = make_float4(q[h4][d], q[h4 + 1][d], q[h4 + 2][d], q[h4 + 3][d]);
        *reinterpret_cast<float4*>(out + base + (size_t)d * H_LAT + h4) = qv;
        float d0 = xv.x - qv.x, d1 = xv.y - qv.y, d2 = xv.z - qv.z, d3 = xv.w - qv.w;
        s += d0 * d0 + d1 * d1 + d2 * d2 + d3 * d3;
    }
    #pragma unroll
    for (int off = 32; off; off >>= 1) s += __shfl_down(s, off);
    if (lane == 0) wsum[w] = s;
    __syncthreads();
    if (t == 0) atomicAdd(lossacc, wsum[0] + wsum[1] + wsum[2] + wsum[3]);
}

/* entropy / perplexity + final loss. 1 block. */
__global__ void finish_kernel(const int* __restrict__ counts,
                              const float* __restrict__ lossacc,
                              float* __restrict__ out)
{
    __shared__ float red[16];
    int t = threadIdx.x;
    float entsum = 0.f, pplsum = 0.f;
    for (int n = 0; n < N_CB; n++) {
        float p = counts[n * M_EMB + t] * (1.f / L_PER);
        float s = p * logf(p + 1e-10f);
        #pragma unroll
        for (int off = 32; off; off >>= 1) s += __shfl_down(s, off);
        int lane = t & 63, w = t >> 6;
        if (lane == 0) red[w] = s;
        __syncthreads();
        if (t < 16) {
            float v = red[t];
            #pragma unroll
            for (int off = 8; off; off >>= 1) v += __shfl_down(v, off);
            if (t == 0) red[0] = v;
        }
        __syncthreads();
        float ent = -red[0];
        entsum += ent;
        pplsum += expf(ent);
        __syncthreads();
    }
    if (t == 0) {
        out[ENT_OFF]  = entsum * (1.f / N_CB);
        out[PPL_OFF]  = pplsum * (1.f / N_CB);
        out[LOSS_OFF] = 0.25f * (*lossacc) / (float)TOTAL_X;
    }
}

extern "C" void kernel_launch(void* const* d_in, const int* in_sizes, int n_in,
                              void* d_out, int out_size, void* d_ws, size_t ws_size,
                              hipStream_t stream)
{
    const float* x   = (const float*)d_in[0];
    const float* emb = (const float*)d_in[1];
    float* out = (float*)d_out;

    float* esq     = (float*)d_ws + WS_ESQ_OFF;
    int*   idx_ws  = (int*)d_ws + WS_IDX_OFF;
    int*   counts  = (int*)d_ws + WS_CNT_OFF;
    float* lossacc = (float*)d_ws + WS_LOSS_OFF;
    int*   paircnt = (int*)d_ws + WS_PCNT_OFF;

    unsigned long long* pairs  = (unsigned long long*)(out + OUT_PAIRS_F);
    unsigned long long* rowmin = (unsigned long long*)(out + OUT_RMIN_F);
    float*              rowthr = out + OUT_THR_F;
    float*              rowxsq = out + OUT_XSQ_F;

    hipLaunchKernelGGL(init_ws, dim3(512), dim3(256), 0, stream,
                       counts, lossacc, paircnt, rowmin);
    hipLaunchKernelGGL(esq_kernel, dim3(2048), dim3(256), 0, stream, emb, esq);
    hipLaunchKernelGGL(xsq_kernel, dim3(2048), dim3(64), 0, stream, x, rowxsq);
    hipLaunchKernelGGL(vq_mfma_kernel, dim3(1024), dim3(256), 0, stream,
                       x, emb, esq, idx_ws, counts, paircnt, pairs, rowthr, out);
    hipLaunchKernelGGL(pair_np_kernel, dim3(2048), dim3(256), 0, stream,
                       x, emb, esq, paircnt, pairs, rowthr, rowxsq, rowmin);
    hipLaunchKernelGGL(apply_fix_kernel, dim3(512), dim3(256), 0, stream,
                       rowmin, idx_ws, counts, out);
    hipLaunchKernelGGL(scatter_loss_kernel, dim3(2048), dim3(256), 0, stream,
                       x, emb, idx_ws, out, lossacc);
    hipLaunchKernelGGL(finish_kernel, dim3(1), dim3(1024), 0, stream,
                       counts, lossacc, out);
}